// Round 4
// baseline (692.339 us; speedup 1.0000x reference)
//
#include <hip/hip_runtime.h>
#include <hip/hip_bf16.h>
#include <cmath>

typedef __attribute__((ext_vector_type(8))) short short8;
typedef __attribute__((ext_vector_type(4))) float f32x4;

#define MFMA16(a, b, c) __builtin_amdgcn_mfma_f32_16x16x32_bf16((a), (b), (c), 0, 0, 0)

static constexpr int BB = 16, NN = 2048, DD = 256, HH = 256;

__device__ inline unsigned short f2bf(float f) {
    union { float f; unsigned int u; } v; v.f = f;
    unsigned int r = v.u + 0x7fffu + ((v.u >> 16) & 1u);
    return (unsigned short)(r >> 16);
}
__device__ inline float bf2f(unsigned short u) {
    union { unsigned int u; float f; } v; v.u = ((unsigned int)u) << 16;
    return v.f;
}
__device__ inline float gelu_exact(float x) {
    return 0.5f * x * (1.0f + erff(x * 0.7071067811865475f));
}

// ---- merged weight transpose: fp32 [K][N] -> bf16 [N][K] for W1b, Wqkv, W2a ----
__global__ void transpose3_k(const float* __restrict__ W1b, const float* __restrict__ Wqkv,
                             const float* __restrict__ W2a, unsigned short* __restrict__ W1bT,
                             unsigned short* __restrict__ WqkvT, unsigned short* __restrict__ W2aT) {
    int tid = blockIdx.x * 256 + threadIdx.x;  // 1280 blocks -> 327680 elems
    if (tid < 65536) {
        int n = tid >> 8, kk = tid & 255;
        W1bT[tid] = f2bf(W1b[kk * 256 + n]);
    } else if (tid < 262144) {
        int t = tid - 65536;
        int n = t >> 8, kk = t & 255;  // n in [0,768), k in [0,256)
        WqkvT[t] = f2bf(Wqkv[kk * 768 + n]);
    } else {
        int t = tid - 262144;
        int n = t >> 8, kk = t & 255;
        W2aT[t] = f2bf(W2a[kk * 256 + n]);
    }
}

// ---- FFN1a ----
__global__ void ffn1a_k(const float* __restrict__ x, const float* __restrict__ grd,
                        const float* __restrict__ W1a, const float* __restrict__ b1a,
                        unsigned short* __restrict__ t_out) {
    int p = blockIdx.x;
    int j = threadIdx.x;
    float xv = x[p];
    float gv = grd[p & (NN - 1)];
    float v = xv * W1a[j] + gv * W1a[HH + j] + b1a[j];
    t_out[(size_t)p * HH + j] = f2bf(gelu_exact(v));
}

// ---- MFMA GEMM: C = A[M,256] @ (BT[N,256])^T, 64x128 tile/block ----
template <int EPI>
__global__ __launch_bounds__(256) void gemm_k(const unsigned short* __restrict__ A,
                                              const unsigned short* __restrict__ BT,
                                              const float* __restrict__ bias,
                                              unsigned short* __restrict__ out0,
                                              unsigned short* __restrict__ qo,
                                              unsigned short* __restrict__ ko,
                                              unsigned short* __restrict__ vo) {
    int w = threadIdx.x >> 6, lane = threadIdx.x & 63;
    int c = lane & 15, g = lane >> 4;
    int rb = blockIdx.x * 64 + w * 16;
    int cb = blockIdx.y * 128;

    const short8* ap = (const short8*)(A + (size_t)(rb + c) * 256 + g * 8);
    const unsigned short* bp0 = BT + (size_t)(cb + c) * 256 + g * 8;

    f32x4 acc[8];
#pragma unroll
    for (int n = 0; n < 8; n++) acc[n] = (f32x4){0.f, 0.f, 0.f, 0.f};

#pragma unroll
    for (int kc = 0; kc < 8; kc++) {
        short8 a = ap[kc * 4];
#pragma unroll
        for (int n = 0; n < 8; n++) {
            short8 bfr = *(const short8*)(bp0 + (size_t)n * 16 * 256 + kc * 32);
            acc[n] = MFMA16(a, bfr, acc[n]);
        }
    }

#pragma unroll
    for (int n = 0; n < 8; n++) {
        int col = cb + n * 16 + c;
#pragma unroll
        for (int r = 0; r < 4; r++) {
            int row = rb + g * 4 + r;
            float v = acc[n][r];
            if (EPI == 0) {
                out0[(size_t)row * 256 + col] = f2bf(v + bias[col]);
            } else if (EPI == 2) {
                out0[(size_t)row * 256 + col] = f2bf(gelu_exact(v + bias[col]));
            } else {
                if (col < 256) {
                    qo[(size_t)row * 256 + col] = f2bf(v * 0.0625f);
                } else if (col < 512) {
                    ko[(size_t)row * 256 + (col - 256)] = f2bf(v);
                } else {
                    int bb = row >> 11;
                    int n_in_b = row & (NN - 1);
                    vo[((size_t)(bb * 256 + (col - 512))) * NN + n_in_b] = f2bf(v);
                }
            }
        }
    }
}

// ---- flash attention: 1-wave blocks, barrier-free, K/V direct from L2 ----
__global__ __launch_bounds__(64) void attn_k(const unsigned short* __restrict__ qb,
                                             const unsigned short* __restrict__ kb,
                                             const unsigned short* __restrict__ vTb,
                                             unsigned short* __restrict__ ob) {
    __shared__ __attribute__((aligned(16))) unsigned int p_lds[16 * 32];  // 2KB bf16 P
    const int lane = threadIdx.x;
    const int c = lane & 15, g = lane >> 4;
    // bijective XCD swizzle: 2048 blocks, 256 consecutive tiles per XCD
    const int bid = blockIdx.x;
    const int swz = (bid & 7) * 256 + (bid >> 3);
    const int b = swz >> 7;          // batch
    const int qt = swz & 127;        // q-tile (16 rows)
    const int qbase = qt * 16;
    constexpr int NT = NN / 64;      // 32 key-tiles

    // Q fragments (16 rows x 256 d) — q pre-scaled by 1/16
    const short8* qp = (const short8*)(qb + (size_t)(b * NN + qbase + c) * DD + g * 8);
    short8 qf[8];
#pragma unroll
    for (int kc = 0; kc < 8; kc++) qf[kc] = qp[kc * 4];

    const unsigned short* kbp = kb + (size_t)(b * NN) * DD;   // batch K base
    const unsigned short* vbp = vTb + (size_t)(b * DD + c) * NN + g * 8;
    const int pswz = (c & 7) << 2;   // P dword-index XOR

    f32x4 oacc[16];
#pragma unroll
    for (int i = 0; i < 16; i++) oacc[i] = (f32x4){0.f, 0.f, 0.f, 0.f};
    float mrun = -INFINITY;  // running max for q-row c (dup across g-lanes)
    float lrun = 0.f;        // per-lane PARTIAL sum (this lane's 16 keys)

    for (int kt = 0; kt < NT; kt++) {
        // ---- swapped QK^T: S^T[64key x 16q]; lane holds key=16t+4g+r, q=c ----
        const unsigned short* kp = kbp + (size_t)(kt * 64 + c) * DD + g * 8;
        f32x4 s[4];
#pragma unroll
        for (int t = 0; t < 4; t++) s[t] = (f32x4){0.f, 0.f, 0.f, 0.f};
        __builtin_amdgcn_s_setprio(1);
#pragma unroll
        for (int kc = 0; kc < 8; kc++) {
            short8 qv = qf[kc];
#pragma unroll
            for (int t = 0; t < 4; t++) {
                short8 kf = *(const short8*)(kp + (size_t)(16 * t) * DD + kc * 32);
                s[t] = MFMA16(kf, qv, s[t]);  // swapped: A=K, B=Q
            }
        }
        __builtin_amdgcn_s_setprio(0);

        // ---- prefetch V first half (keys +0..31) while softmax runs ----
        const unsigned short* vp = vbp + kt * 64;
        short8 vfA[16];
#pragma unroll
        for (int nc = 0; nc < 16; nc++) vfA[nc] = *(const short8*)(vp + (size_t)nc * 16 * NN);

        // ---- in-lane softmax over this lane's 16 keys for q=c ----
        float tm[4];
#pragma unroll
        for (int t = 0; t < 4; t++)
            tm[t] = fmaxf(fmaxf(s[t][0], s[t][1]), fmaxf(s[t][2], s[t][3]));
        float tmax = fmaxf(fmaxf(tm[0], tm[1]), fmaxf(tm[2], tm[3]));
        tmax = fmaxf(tmax, __shfl_xor(tmax, 16));
        tmax = fmaxf(tmax, __shfl_xor(tmax, 32));  // row max for q=c

        bool need = tmax > mrun + 8.f;
        if (__any(need)) {
            float mn = fmaxf(mrun, tmax);
            float corr = __expf(mrun - mn);
#pragma unroll
            for (int t = 0; t < 4; t++)
#pragma unroll
                for (int r = 0; r < 4; r++) s[t][r] = __expf(s[t][r] - mn);
            float a0 = (s[0][0] + s[0][1]) + (s[0][2] + s[0][3]);
            float a1 = (s[1][0] + s[1][1]) + (s[1][2] + s[1][3]);
            float a2 = (s[2][0] + s[2][1]) + (s[2][2] + s[2][3]);
            float a3 = (s[3][0] + s[3][1]) + (s[3][2] + s[3][3]);
            lrun = lrun * corr + ((a0 + a1) + (a2 + a3));
            mrun = mn;
            // rescale oacc rows: oacc holds q=4g+r -> fetch corr from lane with c'=4g+r
#pragma unroll
            for (int r = 0; r < 4; r++) {
                float cr = __shfl(corr, 4 * g + r + 16 * g);
#pragma unroll
                for (int nc = 0; nc < 16; nc++) oacc[nc][r] *= cr;
            }
        } else {
#pragma unroll
            for (int t = 0; t < 4; t++)
#pragma unroll
                for (int r = 0; r < 4; r++) s[t][r] = __expf(s[t][r] - mrun);
            float a0 = (s[0][0] + s[0][1]) + (s[0][2] + s[0][3]);
            float a1 = (s[1][0] + s[1][1]) + (s[1][2] + s[1][3]);
            float a2 = (s[2][0] + s[2][1]) + (s[2][2] + s[2][3]);
            float a3 = (s[3][0] + s[3][1]) + (s[3][2] + s[3][3]);
            lrun += (a0 + a1) + (a2 + a3);
        }

        // ---- pack P to bf16, XOR-swizzled per-wave LDS [q=c][64 keys] ----
#pragma unroll
        for (int t = 0; t < 4; t++) {
#pragma unroll
            for (int h = 0; h < 2; h++) {
                unsigned int pw = (unsigned int)f2bf(s[t][2 * h]) |
                                  ((unsigned int)f2bf(s[t][2 * h + 1]) << 16);
                p_lds[c * 32 + ((8 * t + 2 * g + h) ^ pswz)] = pw;
            }
        }
        short8 pf0 = *(const short8*)(p_lds + c * 32 + ((4 * g) ^ pswz));
        short8 pf1 = *(const short8*)(p_lds + c * 32 + ((16 + 4 * g) ^ pswz));

        // ---- PV: O[16q x 256d] += P @ V (second V half loaded here) ----
        short8 vfB[16];
#pragma unroll
        for (int nc = 0; nc < 16; nc++) vfB[nc] = *(const short8*)(vp + (size_t)nc * 16 * NN + 32);
        __builtin_amdgcn_s_setprio(1);
#pragma unroll
        for (int nc = 0; nc < 16; nc++) oacc[nc] = MFMA16(pf0, vfA[nc], oacc[nc]);
#pragma unroll
        for (int nc = 0; nc < 16; nc++) oacc[nc] = MFMA16(pf1, vfB[nc], oacc[nc]);
        __builtin_amdgcn_s_setprio(0);
    }

    // ---- epilogue: reduce l across g-lanes, redistribute, store ----
    float lt = lrun;
    lt += __shfl_xor(lt, 16);
    lt += __shfl_xor(lt, 32);  // total sum for q=c
    float inv_r[4];
#pragma unroll
    for (int r = 0; r < 4; r++) inv_r[r] = 1.f / __shfl(lt, 4 * g + r + 16 * g);
#pragma unroll
    for (int r = 0; r < 4; r++) {
        size_t rowoff = (size_t)(b * NN + qbase + 4 * g + r) * DD;
#pragma unroll
        for (int nc = 0; nc < 16; nc++) {
            ob[rowoff + nc * 16 + c] = f2bf(oacc[nc][r] * inv_r[r]);
        }
    }
}

// ---- mean over N (vectorized short8 loads) ----
__global__ void mean_k(const unsigned short* __restrict__ gbuf, float* __restrict__ bar) {
    int b = blockIdx.x, chunk = blockIdx.y;
    int t = threadIdx.x;
    int hg = (t & 31) * 8;
    int strip = t >> 5;
    const unsigned short* p =
        gbuf + ((size_t)(b * NN + chunk * 256 + strip * 32) * HH) + hg;
    float s[8] = {0.f, 0.f, 0.f, 0.f, 0.f, 0.f, 0.f, 0.f};
    for (int i = 0; i < 32; i++) {
        short8 v = *(const short8*)(p + (size_t)i * HH);
#pragma unroll
        for (int j = 0; j < 8; j++) s[j] += bf2f((unsigned short)v[j]);
    }
#pragma unroll
    for (int j = 0; j < 8; j++) atomicAdd(&bar[b * HH + hg + j], s[j]);
}

// ---- final projection ----
__global__ void final_k(const float* __restrict__ bar, const float* __restrict__ W2b,
                        const float* __restrict__ b2b, float* __restrict__ out) {
    int b = blockIdx.x, d = threadIdx.x;
    float s = 0.f;
    for (int h = 0; h < HH; h++) s += bar[b * HH + h] * W2b[h * DD + d];
    out[b * DD + d] = b2b[d] + s * (1.f / (float)NN);
}

extern "C" void kernel_launch(void* const* d_in, const int* in_sizes, int n_in,
                              void* d_out, int out_size, void* d_ws, size_t ws_size,
                              hipStream_t stream) {
    (void)in_sizes; (void)n_in; (void)out_size; (void)ws_size;
    const float* x    = (const float*)d_in[0];
    const float* grd  = (const float*)d_in[1];
    const float* W1a  = (const float*)d_in[2];
    const float* b1a  = (const float*)d_in[3];
    const float* W1b  = (const float*)d_in[4];
    const float* b1b  = (const float*)d_in[5];
    const float* Wqkv = (const float*)d_in[6];
    const float* W2a  = (const float*)d_in[7];
    const float* b2a  = (const float*)d_in[8];
    const float* W2b  = (const float*)d_in[9];
    const float* b2b  = (const float*)d_in[10];
    float* out = (float*)d_out;

    char* ws = (char*)d_ws;
    const size_t MB = 1024 * 1024;
    unsigned short* t_buf  = (unsigned short*)(ws + 0);
    unsigned short* h_buf  = (unsigned short*)(ws + 16 * MB);
    unsigned short* q_buf  = (unsigned short*)(ws + 32 * MB);
    unsigned short* k_buf  = (unsigned short*)(ws + 48 * MB);
    unsigned short* vT_buf = (unsigned short*)(ws + 64 * MB);
    unsigned short* W1bT   = (unsigned short*)(ws + 80 * MB);
    unsigned short* WqkvT  = (unsigned short*)(ws + 80 * MB + 512 * 1024);
    unsigned short* W2aT   = (unsigned short*)(ws + 81 * MB);
    float*          bar    = (float*)(ws + 81 * MB + 512 * 1024);

    transpose3_k<<<dim3(1280), 256, 0, stream>>>(W1b, Wqkv, W2a, W1bT, WqkvT, W2aT);
    ffn1a_k<<<dim3(BB * NN), 256, 0, stream>>>(x, grd, W1a, b1a, t_buf);
    gemm_k<0><<<dim3(512, 2), 256, 0, stream>>>(t_buf, W1bT, b1b, h_buf, nullptr, nullptr, nullptr);
    gemm_k<1><<<dim3(512, 6), 256, 0, stream>>>(h_buf, WqkvT, nullptr, nullptr, q_buf, k_buf, vT_buf);
    attn_k<<<dim3(2048), 64, 0, stream>>>(q_buf, k_buf, vT_buf, t_buf);
    gemm_k<2><<<dim3(512, 2), 256, 0, stream>>>(t_buf, W2aT, b2a, h_buf, nullptr, nullptr, nullptr);
    hipMemsetAsync(bar, 0, BB * HH * sizeof(float), stream);
    mean_k<<<dim3(BB, 8), 256, 0, stream>>>(h_buf, bar);
    final_k<<<dim3(BB), 256, 0, stream>>>(bar, W2b, b2b, out);
}

// Round 5
// 452.541 us; speedup vs baseline: 1.5299x; 1.5299x over previous
//
#include <hip/hip_runtime.h>
#include <hip/hip_bf16.h>
#include <cmath>

typedef __attribute__((ext_vector_type(8))) short short8;
typedef __attribute__((ext_vector_type(4))) float f32x4;

#define MFMA16(a, b, c) __builtin_amdgcn_mfma_f32_16x16x32_bf16((a), (b), (c), 0, 0, 0)

static constexpr int BB = 16, NN = 2048, DD = 256, HH = 256;

__device__ inline unsigned short f2bf(float f) {
    union { float f; unsigned int u; } v; v.f = f;
    unsigned int r = v.u + 0x7fffu + ((v.u >> 16) & 1u);
    return (unsigned short)(r >> 16);
}
__device__ inline float bf2f(unsigned short u) {
    union { unsigned int u; float f; } v; v.u = ((unsigned int)u) << 16;
    return v.f;
}
__device__ inline float gelu_exact(float x) {
    return 0.5f * x * (1.0f + erff(x * 0.7071067811865475f));
}
__device__ inline void gload_lds16(const void* g, void* l) {
    __builtin_amdgcn_global_load_lds(
        (const __attribute__((address_space(1))) unsigned int*)g,
        (__attribute__((address_space(3))) unsigned int*)l, 16, 0, 0);
}
__device__ inline void fence_mem() { asm volatile("" ::: "memory"); }

// ---- merged weight transpose: fp32 [K][N] -> bf16 [N][K] for W1b, Wqkv, W2a ----
__global__ void transpose3_k(const float* __restrict__ W1b, const float* __restrict__ Wqkv,
                             const float* __restrict__ W2a, unsigned short* __restrict__ W1bT,
                             unsigned short* __restrict__ WqkvT, unsigned short* __restrict__ W2aT) {
    int tid = blockIdx.x * 256 + threadIdx.x;  // 1280 blocks -> 327680 elems
    if (tid < 65536) {
        int n = tid >> 8, kk = tid & 255;
        W1bT[tid] = f2bf(W1b[kk * 256 + n]);
    } else if (tid < 262144) {
        int t = tid - 65536;
        int n = t >> 8, kk = t & 255;
        WqkvT[t] = f2bf(Wqkv[kk * 768 + n]);
    } else {
        int t = tid - 262144;
        int n = t >> 8, kk = t & 255;
        W2aT[t] = f2bf(W2a[kk * 256 + n]);
    }
}

// ---- FFN1a ----
__global__ void ffn1a_k(const float* __restrict__ x, const float* __restrict__ grd,
                        const float* __restrict__ W1a, const float* __restrict__ b1a,
                        unsigned short* __restrict__ t_out) {
    int p = blockIdx.x;
    int j = threadIdx.x;
    float xv = x[p];
    float gv = grd[p & (NN - 1)];
    float v = xv * W1a[j] + gv * W1a[HH + j] + b1a[j];
    t_out[(size_t)p * HH + j] = f2bf(gelu_exact(v));
}

// ---- MFMA GEMM: C = A[M,256] @ (BT[N,256])^T, 64x128 tile/block ----
template <int EPI>
__global__ __launch_bounds__(256) void gemm_k(const unsigned short* __restrict__ A,
                                              const unsigned short* __restrict__ BT,
                                              const float* __restrict__ bias,
                                              unsigned short* __restrict__ out0,
                                              unsigned short* __restrict__ qo,
                                              unsigned short* __restrict__ ko,
                                              unsigned short* __restrict__ vo) {
    int w = threadIdx.x >> 6, lane = threadIdx.x & 63;
    int c = lane & 15, g = lane >> 4;
    int rb = blockIdx.x * 64 + w * 16;
    int cb = blockIdx.y * 128;

    const short8* ap = (const short8*)(A + (size_t)(rb + c) * 256 + g * 8);
    const unsigned short* bp0 = BT + (size_t)(cb + c) * 256 + g * 8;

    f32x4 acc[8];
#pragma unroll
    for (int n = 0; n < 8; n++) acc[n] = (f32x4){0.f, 0.f, 0.f, 0.f};

#pragma unroll
    for (int kc = 0; kc < 8; kc++) {
        short8 a = ap[kc * 4];
#pragma unroll
        for (int n = 0; n < 8; n++) {
            short8 bfr = *(const short8*)(bp0 + (size_t)n * 16 * 256 + kc * 32);
            acc[n] = MFMA16(a, bfr, acc[n]);
        }
    }

#pragma unroll
    for (int n = 0; n < 8; n++) {
        int col = cb + n * 16 + c;
#pragma unroll
        for (int r = 0; r < 4; r++) {
            int row = rb + g * 4 + r;
            float v = acc[n][r];
            if (EPI == 0) {
                out0[(size_t)row * 256 + col] = f2bf(v + bias[col]);
            } else if (EPI == 2) {
                out0[(size_t)row * 256 + col] = f2bf(gelu_exact(v + bias[col]));
            } else {
                if (col < 256) {
                    qo[(size_t)row * 256 + col] = f2bf(v * 0.0625f);
                } else if (col < 512) {
                    ko[(size_t)row * 256 + (col - 256)] = f2bf(v);
                } else {
                    int bb = row >> 11;
                    int n_in_b = row & (NN - 1);
                    vo[((size_t)(bb * 256 + (col - 512))) * NN + n_in_b] = f2bf(v);
                }
            }
        }
    }
}

// ---- flash attention: KVBLK=32, K AND V LDS-staged (dbuf), swapped QK^T ----
__global__ __launch_bounds__(256) void attn_k(const unsigned short* __restrict__ qb,
                                              const unsigned short* __restrict__ kb,
                                              const unsigned short* __restrict__ vTb,
                                              unsigned short* __restrict__ ob) {
    __shared__ __attribute__((aligned(16))) char klds[2][32 * 512];          // 32KB swizzled K
    __shared__ __attribute__((aligned(16))) char vlds[2][256 * 64];          // 32KB V^T linear
    __shared__ __attribute__((aligned(16))) unsigned int p_lds[4][16 * 32];  // 8KB bf16 P
    const int tid = threadIdx.x;
    const int w = tid >> 6, lane = tid & 63;
    const int c = lane & 15, g = lane >> 4;
    // bijective XCD swizzle: 512 blocks, 64/XCD = 2 batches/XCD
    const int bid = blockIdx.x;
    const int swz = (bid & 7) * 64 + (bid >> 3);
    const int b = swz >> 5;
    const int qt = swz & 31;
    const int qbase = qt * 64 + w * 16;
    constexpr int NT = NN / 32;  // 64 key-tiles

    // staging lane geometry
    const int sl_sub = lane >> 5;          // K: row parity within pair
    const int sl_col = (lane & 31) * 16;   // K: byte col 0..496
    const int vrow = lane >> 2;            // V: d-row within 16-row chunk
    const int vcol = (lane & 3) * 16;      // V: byte col within 64B row

    // Q fragments (16 rows x 256 d) — q pre-scaled by 1/16
    const short8* qp = (const short8*)(qb + (size_t)(b * NN + qbase + c) * DD + g * 8);
    short8 qf[8];
#pragma unroll
    for (int kc = 0; kc < 8; kc++) qf[kc] = qp[kc * 4];

    const char* kb_bytes = (const char*)(kb + (size_t)(b * NN) * DD);
    const char* vb_bytes = (const char*)(vTb + (size_t)(b * DD) * NN);
    const int kswz = (c & 7) << 4;   // K read-side XOR
    const int pswz = (c & 7) << 2;   // P dword-index XOR

    // per iter per wave: 4 K-instrs (rows 8w..8w+7) + 4 V-instrs (d-rows 64w..64w+63)
#define STAGE_KV(bufsel, kt_) do {                                                       \
        const char* gk = kb_bytes + ((size_t)((kt_) * 32 + 8 * w)) * 512;                \
        _Pragma("unroll")                                                                \
        for (int s_ = 0; s_ < 4; s_++) {                                                 \
            int row_lo = 2 * s_ + sl_sub;                                                \
            gload_lds16(gk + (size_t)row_lo * 512 + (sl_col ^ (row_lo << 4)),            \
                        &klds[bufsel][0] + (w * 4 + s_) * 1024);                         \
        }                                                                                \
        const char* gv = vb_bytes + ((size_t)(64 * w + vrow) * NN + (kt_) * 32) * 2 + vcol; \
        _Pragma("unroll")                                                                \
        for (int s_ = 0; s_ < 4; s_++) {                                                 \
            gload_lds16(gv + (size_t)(16 * s_) * NN * 2,                                 \
                        &vlds[bufsel][0] + (w * 4 + s_) * 1024);                         \
        }                                                                                \
    } while (0)

    f32x4 oacc[16];
#pragma unroll
    for (int i = 0; i < 16; i++) oacc[i] = (f32x4){0.f, 0.f, 0.f, 0.f};
    float mrun = -INFINITY;  // running max for q-row c (dup across g-lanes)
    float lrun = 0.f;        // per-lane PARTIAL sum (this lane's 8 keys/tile)
    unsigned int* pl = &p_lds[w][0];

    STAGE_KV(0, 0);

    for (int kt = 0; kt < NT; kt++) {
        int cur = kt & 1;
        if (kt + 1 < NT) {
            STAGE_KV(cur ^ 1, kt + 1);
            asm volatile("s_waitcnt vmcnt(8)" ::: "memory");
        } else {
            asm volatile("s_waitcnt vmcnt(0)" ::: "memory");
        }
        __builtin_amdgcn_s_barrier();  // B1: tile `cur` staged
        fence_mem();

        const char* kl = &klds[cur][0];
        const char* vl = &vlds[cur][0];

        // ---- swapped QK^T: S^T[32key x 16q]; lane holds keys {16t+4g+r}, q=c ----
        f32x4 s0 = (f32x4){0.f, 0.f, 0.f, 0.f};
        f32x4 s1 = (f32x4){0.f, 0.f, 0.f, 0.f};
        __builtin_amdgcn_s_setprio(1);
#pragma unroll
        for (int kc = 0; kc < 8; kc++) {
            short8 qv = qf[kc];
            int col = (kc * 64 + g * 16) ^ kswz;
            short8 kf0 = *(const short8*)(kl + (size_t)c * 512 + col);
            short8 kf1 = *(const short8*)(kl + (size_t)(c + 16) * 512 + col);
            s0 = MFMA16(kf0, qv, s0);
            s1 = MFMA16(kf1, qv, s1);
        }
        __builtin_amdgcn_s_setprio(0);

        // ---- in-lane softmax over this lane's 8 keys for q=c ----
        float t0 = fmaxf(fmaxf(s0[0], s0[1]), fmaxf(s0[2], s0[3]));
        float t1 = fmaxf(fmaxf(s1[0], s1[1]), fmaxf(s1[2], s1[3]));
        float tmax = fmaxf(t0, t1);
        tmax = fmaxf(tmax, __shfl_xor(tmax, 16));
        tmax = fmaxf(tmax, __shfl_xor(tmax, 32));  // row max for q=c

        bool need = tmax > mrun + 8.f;
        if (__any(need)) {
            float mn = fmaxf(mrun, tmax);
            float corr = __expf(mrun - mn);
#pragma unroll
            for (int r = 0; r < 4; r++) s0[r] = __expf(s0[r] - mn);
#pragma unroll
            for (int r = 0; r < 4; r++) s1[r] = __expf(s1[r] - mn);
            lrun = lrun * corr + ((s0[0] + s0[1]) + (s0[2] + s0[3])) +
                   ((s1[0] + s1[1]) + (s1[2] + s1[3]));
            mrun = mn;
#pragma unroll
            for (int r = 0; r < 4; r++) {
                float cr = __shfl(corr, 20 * g + r);  // lane with c'=4g+r
#pragma unroll
                for (int nc = 0; nc < 16; nc++) oacc[nc][r] *= cr;
            }
        } else {
#pragma unroll
            for (int r = 0; r < 4; r++) s0[r] = __expf(s0[r] - mrun);
#pragma unroll
            for (int r = 0; r < 4; r++) s1[r] = __expf(s1[r] - mrun);
            lrun += ((s0[0] + s0[1]) + (s0[2] + s0[3])) +
                    ((s1[0] + s1[1]) + (s1[2] + s1[3]));
        }

        // ---- pack P to bf16, XOR-swizzled per-wave LDS [q=c][32 key-dwords] ----
        {
            unsigned int pw;
            pw = (unsigned int)f2bf(s0[0]) | ((unsigned int)f2bf(s0[1]) << 16);
            pl[c * 32 + ((2 * g + 0) ^ pswz)] = pw;
            pw = (unsigned int)f2bf(s0[2]) | ((unsigned int)f2bf(s0[3]) << 16);
            pl[c * 32 + ((2 * g + 1) ^ pswz)] = pw;
            pw = (unsigned int)f2bf(s1[0]) | ((unsigned int)f2bf(s1[1]) << 16);
            pl[c * 32 + ((8 + 2 * g + 0) ^ pswz)] = pw;
            pw = (unsigned int)f2bf(s1[2]) | ((unsigned int)f2bf(s1[3]) << 16);
            pl[c * 32 + ((8 + 2 * g + 1) ^ pswz)] = pw;
        }
        short8 pf = *(const short8*)(pl + c * 32 + ((4 * g) ^ pswz));

        // ---- PV: O[16q x 256d] += P(16x32) @ V(32x256), V from LDS ----
        __builtin_amdgcn_s_setprio(1);
#pragma unroll
        for (int nc = 0; nc < 16; nc++) {
            short8 vf = *(const short8*)(vl + (size_t)(16 * nc + c) * 64 + g * 16);
            oacc[nc] = MFMA16(pf, vf, oacc[nc]);
        }
        __builtin_amdgcn_s_setprio(0);

        fence_mem();
        __builtin_amdgcn_s_barrier();  // B2: all waves done reading tile `cur`
        fence_mem();
    }
#undef STAGE_KV

    // ---- epilogue: reduce l across g-lanes, redistribute, store ----
    float lt = lrun;
    lt += __shfl_xor(lt, 16);
    lt += __shfl_xor(lt, 32);  // total sum for q=c
    float inv_r[4];
#pragma unroll
    for (int r = 0; r < 4; r++) inv_r[r] = 1.f / __shfl(lt, 20 * g + r);
#pragma unroll
    for (int r = 0; r < 4; r++) {
        size_t rowoff = (size_t)(b * NN + qbase + 4 * g + r) * DD;
#pragma unroll
        for (int nc = 0; nc < 16; nc++) {
            ob[rowoff + nc * 16 + c] = f2bf(oacc[nc][r] * inv_r[r]);
        }
    }
}

// ---- mean over N (vectorized short8 loads) ----
__global__ void mean_k(const unsigned short* __restrict__ gbuf, float* __restrict__ bar) {
    int b = blockIdx.x, chunk = blockIdx.y;
    int t = threadIdx.x;
    int hg = (t & 31) * 8;
    int strip = t >> 5;
    const unsigned short* p =
        gbuf + ((size_t)(b * NN + chunk * 256 + strip * 32) * HH) + hg;
    float s[8] = {0.f, 0.f, 0.f, 0.f, 0.f, 0.f, 0.f, 0.f};
    for (int i = 0; i < 32; i++) {
        short8 v = *(const short8*)(p + (size_t)i * HH);
#pragma unroll
        for (int j = 0; j < 8; j++) s[j] += bf2f((unsigned short)v[j]);
    }
#pragma unroll
    for (int j = 0; j < 8; j++) atomicAdd(&bar[b * HH + hg + j], s[j]);
}

// ---- final projection ----
__global__ void final_k(const float* __restrict__ bar, const float* __restrict__ W2b,
                        const float* __restrict__ b2b, float* __restrict__ out) {
    int b = blockIdx.x, d = threadIdx.x;
    float s = 0.f;
    for (int h = 0; h < HH; h++) s += bar[b * HH + h] * W2b[h * DD + d];
    out[b * DD + d] = b2b[d] + s * (1.f / (float)NN);
}

extern "C" void kernel_launch(void* const* d_in, const int* in_sizes, int n_in,
                              void* d_out, int out_size, void* d_ws, size_t ws_size,
                              hipStream_t stream) {
    (void)in_sizes; (void)n_in; (void)out_size; (void)ws_size;
    const float* x    = (const float*)d_in[0];
    const float* grd  = (const float*)d_in[1];
    const float* W1a  = (const float*)d_in[2];
    const float* b1a  = (const float*)d_in[3];
    const float* W1b  = (const float*)d_in[4];
    const float* b1b  = (const float*)d_in[5];
    const float* Wqkv = (const float*)d_in[6];
    const float* W2a  = (const float*)d_in[7];
    const float* b2a  = (const float*)d_in[8];
    const float* W2b  = (const float*)d_in[9];
    const float* b2b  = (const float*)d_in[10];
    float* out = (float*)d_out;

    char* ws = (char*)d_ws;
    const size_t MB = 1024 * 1024;
    unsigned short* t_buf  = (unsigned short*)(ws + 0);
    unsigned short* h_buf  = (unsigned short*)(ws + 16 * MB);
    unsigned short* q_buf  = (unsigned short*)(ws + 32 * MB);
    unsigned short* k_buf  = (unsigned short*)(ws + 48 * MB);
    unsigned short* vT_buf = (unsigned short*)(ws + 64 * MB);
    unsigned short* W1bT   = (unsigned short*)(ws + 80 * MB);
    unsigned short* WqkvT  = (unsigned short*)(ws + 80 * MB + 512 * 1024);
    unsigned short* W2aT   = (unsigned short*)(ws + 81 * MB);
    float*          bar    = (float*)(ws + 81 * MB + 512 * 1024);

    transpose3_k<<<dim3(1280), 256, 0, stream>>>(W1b, Wqkv, W2a, W1bT, WqkvT, W2aT);
    ffn1a_k<<<dim3(BB * NN), 256, 0, stream>>>(x, grd, W1a, b1a, t_buf);
    gemm_k<0><<<dim3(512, 2), 256, 0, stream>>>(t_buf, W1bT, b1b, h_buf, nullptr, nullptr, nullptr);
    gemm_k<1><<<dim3(512, 6), 256, 0, stream>>>(h_buf, WqkvT, nullptr, nullptr, q_buf, k_buf, vT_buf);
    attn_k<<<dim3(512), 256, 0, stream>>>(q_buf, k_buf, vT_buf, t_buf);
    gemm_k<2><<<dim3(512, 2), 256, 0, stream>>>(t_buf, W2aT, b2a, h_buf, nullptr, nullptr, nullptr);
    hipMemsetAsync(bar, 0, BB * HH * sizeof(float), stream);
    mean_k<<<dim3(BB, 8), 256, 0, stream>>>(h_buf, bar);
    final_k<<<dim3(BB), 256, 0, stream>>>(bar, W2b, b2b, out);
}